// Round 6
// baseline (200.394 us; speedup 1.0000x reference)
//
#include <hip/hip_runtime.h>
#include <hip/hip_bf16.h>
#include <math.h>

#define B_ 2
#define S_ 2048
#define D_ 1024
#define H_ 16
#define HD_ 64

typedef short bf16x8 __attribute__((ext_vector_type(8)));
typedef short bf16x4 __attribute__((ext_vector_type(4)));
typedef float f32x4 __attribute__((ext_vector_type(4)));

#define MFMA32(a, b, c) __builtin_amdgcn_mfma_f32_16x16x32_bf16(a, b, c, 0, 0, 0)
#define MFMA16(a, b, c) __builtin_amdgcn_mfma_f32_16x16x16bf16_1k(a, b, c, 0, 0, 0)

static __device__ __forceinline__ unsigned short f2bf(float f) {
    union { float f; unsigned u; } v = {f};
    return (unsigned short)((v.u + 0x7fffu + ((v.u >> 16) & 1u)) >> 16);
}

static __device__ __forceinline__ unsigned pk2bf(float a, float b) {
    __hip_bfloat162 h = __float22bfloat162_rn(make_float2(a, b));
    unsigned r;
    __builtin_memcpy(&r, &h, 4);
    return r;
}

static __device__ __forceinline__ void gl2lds16(const void* g, void* l) {
    __builtin_amdgcn_global_load_lds((const __attribute__((address_space(1))) unsigned int*)g,
                                     (__attribute__((address_space(3))) unsigned int*)l,
                                     16, 0, 0);
}

// scale all 8 bf16 lanes of a fragment by s (fp32 math, RNE repack)
static __device__ __forceinline__ bf16x8 scaleQ(bf16x8 v, float s) {
    union { bf16x8 v; unsigned u[4]; } a, r;
    a.v = v;
    #pragma unroll
    for (int i = 0; i < 4; ++i) {
        float lo = __uint_as_float(a.u[i] << 16);
        float hi = __uint_as_float(a.u[i] & 0xffff0000u);
        r.u[i] = pk2bf(lo * s, hi * s);
    }
    return r.v;
}

// ---------------------------------------------------------------------------
// fused fp32 -> bf16 convert for all three inputs (RNE)
// ---------------------------------------------------------------------------
__global__ __launch_bounds__(256) void cvt_all(const float* __restrict__ x,
                                               const float* __restrict__ wq,
                                               const float* __restrict__ wo,
                                               unsigned short* __restrict__ xb,
                                               unsigned short* __restrict__ wqb,
                                               unsigned short* __restrict__ wob) {
    const int N0 = 1048576, N1 = 786432, N2 = 262144;  // float4 counts
    int stride = gridDim.x * blockDim.x;
    for (int i = blockIdx.x * blockDim.x + threadIdx.x; i < N0 + N1 + N2; i += stride) {
        const float4* src; ushort4* dst; int j;
        if (i < N0)            { src = (const float4*)x;  dst = (ushort4*)xb;  j = i; }
        else if (i < N0 + N1)  { src = (const float4*)wq; dst = (ushort4*)wqb; j = i - N0; }
        else                   { src = (const float4*)wo; dst = (ushort4*)wob; j = i - N0 - N1; }
        float4 v = src[j];
        ushort4 o;
        o.x = f2bf(v.x); o.y = f2bf(v.y); o.z = f2bf(v.z); o.w = f2bf(v.w);
        dst[j] = o;
    }
}

// ---------------------------------------------------------------------------
// bf16 NT GEMM. NOW double-buffered (attn-proven pipeline): DMA(k+1) is in
// flight across compute(k); one vmcnt(0)+barrier per K-step instead of the
// m97 2-barrier serialization (whole DMA latency was exposed per step).
// LDS 32 KB (2 bufs). XCD-chunked block swizzle: flattened tile index
// remapped so each XCD owns a contiguous chunk of row-major tiles ->
// A-panels reused within one XCD's L2 (grids are %8==0 -> bijective).
// Fused V-transpose epilogue (QKV projection): V-section blocks
// (col0 >= 2*D_) write transposed into vt, skip qkvb.
// ---------------------------------------------------------------------------
template <int BN>
__global__ __launch_bounds__(256) void gemm_nt_b(const unsigned short* __restrict__ A,
                                                 const unsigned short* __restrict__ Bm,
                                                 void* __restrict__ Cout,
                                                 unsigned short* __restrict__ vtout,
                                                 int M, int N, int K, int c_bf16) {
    constexpr int BM = 128, BK = 32;
    constexpr int MI = (BN == 128) ? 4 : 2;
    constexpr int NI = 4;
    constexpr int SEGS = (BM + BN) / 16;
    __shared__ unsigned short As[2][BM * BK];
    __shared__ unsigned short Bs[2][BN * BK];

    const int tid = threadIdx.x;
    const int wave = tid >> 6, lane = tid & 63;
    const int m16 = lane & 15, quad = lane >> 4;
    const int wrow = (BN == 128) ? (wave >> 1) * 64 : wave * 32;
    const int wcol = (BN == 128) ? (wave & 1) * 64 : 0;

    // XCD-chunked bijective swizzle of the flattened tile index
    const int nbx = gridDim.x;
    const int nblk = nbx * gridDim.y;              // multiple of 8 by launch
    const int lid = blockIdx.y * nbx + blockIdx.x;
    const int id2 = (lid & 7) * (nblk >> 3) + (lid >> 3);
    const int row0 = (id2 / nbx) * BM, col0 = (id2 % nbx) * BN;

    const int lrow = lane >> 2;
    const int lk = (lane & 3) * 8;

    f32x4 acc[MI][NI] = {};

    auto stage = [&](int kk, int buf) {
        for (int s = wave; s < SEGS; s += 4) {
            if (s < BM / 16) {
                gl2lds16(&A[(size_t)(row0 + s * 16 + lrow) * K + kk * BK + lk],
                         &As[buf][s * 16 * BK]);
            } else {
                int t = s - BM / 16;
                gl2lds16(&Bm[(size_t)(col0 + t * 16 + lrow) * K + kk * BK + lk],
                         &Bs[buf][t * 16 * BK]);
            }
        }
    };

    const int nk = K / BK;
    stage(0, 0);
    __asm__ volatile("s_waitcnt vmcnt(0)" ::: "memory");
    __syncthreads();
    stage(1, 1);

    for (int kk = 0; kk < nk; ++kk) {
        const int buf = kk & 1;
        bf16x8 af[MI], bfr[NI];
        #pragma unroll
        for (int mi = 0; mi < MI; ++mi)
            af[mi] = *(const bf16x8*)&As[buf][(wrow + mi * 16 + m16) * BK + quad * 8];
        #pragma unroll
        for (int ni = 0; ni < NI; ++ni)
            bfr[ni] = *(const bf16x8*)&Bs[buf][(wcol + ni * 16 + m16) * BK + quad * 8];
        #pragma unroll
        for (int mi = 0; mi < MI; ++mi)
            #pragma unroll
            for (int ni = 0; ni < NI; ++ni)
                acc[mi][ni] = MFMA32(af[mi], bfr[ni], acc[mi][ni]);

        // DMA(kk+1) had all of compute(kk) to land; drain; refill freed buf
        __asm__ volatile("s_waitcnt vmcnt(0)" ::: "memory");
        __syncthreads();
        if (kk + 2 < nk) stage(kk + 2, buf);
    }

    if (vtout != nullptr && col0 >= 2 * D_) {
        // V block of the QKV projection: write transposed into vt only.
        #pragma unroll
        for (int mi = 0; mi < MI; ++mi) {
            int srow = row0 + wrow + mi * 16 + quad * 4;   // b*2048 + s
            int bb = srow >> 11;
            int s = srow & (S_ - 1);
            #pragma unroll
            for (int ni = 0; ni < NI; ++ni) {
                int hd = col0 + wcol + ni * 16 + m16 - 2 * D_;  // 0..1023
                ushort4 v4;
                v4.x = f2bf(acc[mi][ni][0]);
                v4.y = f2bf(acc[mi][ni][1]);
                v4.z = f2bf(acc[mi][ni][2]);
                v4.w = f2bf(acc[mi][ni][3]);
                *(ushort4*)&vtout[((size_t)(bb * 16 + (hd >> 6)) * 64 + (hd & 63)) * S_ + s] = v4;
            }
        }
        return;
    }

    #pragma unroll
    for (int mi = 0; mi < MI; ++mi) {
        #pragma unroll
        for (int r = 0; r < 4; ++r) {
            size_t grow = row0 + wrow + mi * 16 + quad * 4 + r;
            #pragma unroll
            for (int ni = 0; ni < NI; ++ni) {
                size_t gcol = col0 + wcol + ni * 16 + m16;
                if (c_bf16)
                    ((unsigned short*)Cout)[grow * N + gcol] = f2bf(acc[mi][ni][r]);
                else
                    ((float*)Cout)[grow * N + gcol] = acc[mi][ni][r];
            }
        }
    }
}

// ---------------------------------------------------------------------------
// MFMA flash attention, key-split wave groups (R3 verified: 56.7 us).
// 512 threads = 8 waves. Waves 0-3 (group A) own q-subtiles of 32 queries
// and process EVEN 64-key tiles; waves 4-7 (group B) own the SAME queries
// and process ODD tiles. Each wave amortizes each staged K/V tile over 32
// queries. KT=64: live set = 2 tiles x 16KB x 2 bufs = 64KB -> 2 blocks/CU,
// 4 waves/SIMD. No running max (exp2 direct), so partials merge by pure
// addition: group B writes (o,ol) to LDS once; group A adds + normalizes.
// Pipeline: compute(t) with DMA(t+1) in flight; vmcnt(0); barrier; DMA(t+2).
// ---------------------------------------------------------------------------
__global__ __launch_bounds__(512, 4) void attn_mfma(const unsigned short* __restrict__ qkv,
                                                    const unsigned short* __restrict__ vt,
                                                    unsigned short* __restrict__ out) {
    // [buf][ K_even(4096) | V_even(4096) | K_odd(4096) | V_odd(4096) ] shorts
    __shared__ unsigned short L[2][16384];

    const int id = blockIdx.x;
    const int bh = ((id >> 3) & 3) * 8 + (id & 7);
    const int b = bh >> 4, h = bh & 15;
    const int q0 = (id >> 5) * 128;

    const int tid = threadIdx.x;
    const int wave = tid >> 6, lane = tid & 63;  // wave 0..7
    const int grp = wave >> 2;                   // 0: even tiles, 1: odd tiles
    const int qw = wave & 3;                     // q-subtile (32 q each)
    const int m16 = lane & 15, quad = lane >> 4;

    const float QS = 0.125f * 1.44269504089f;  // scale * log2(e), folded into Q

    bf16x8 qf0[2], qf1[2];
    #pragma unroll
    for (int g = 0; g < 2; ++g) {
        const unsigned short* qrow =
            qkv + ((size_t)b * S_ + q0 + qw * 32 + g * 16 + m16) * (3 * D_) + h * HD_;
        qf0[g] = scaleQ(*(const bf16x8*)(qrow + quad * 8), QS);
        qf1[g] = scaleQ(*(const bf16x8*)(qrow + 32 + quad * 8), QS);
    }

    f32x4 o[2][4] = {};
    f32x4 ol[2] = {};
    const bf16x4 onesf = {(short)0x3F80, (short)0x3F80, (short)0x3F80, (short)0x3F80};

    const unsigned short* kbase = qkv + (size_t)b * S_ * 3 * D_ + D_ + h * HD_;
    const unsigned short* vtbase = vt + (size_t)bh * 64 * S_;

    const int lr8 = lane >> 3;           // row-in-8-group
    const int lsrc = (lane & 7) ^ lr8;   // source chunk for swizzled DMA

    // loop-invariant LDS read offsets (shorts, within a 4096-short region)
    const int kaddr0 = m16 * 64 + ((quad ^ (m16 & 7)) * 8);
    const int kaddr1 = kaddr0 ^ 32;
    int va[4];
    #pragma unroll
    for (int nt = 0; nt < 4; ++nt) {
        int kc = nt * 2 + (quad >> 1);
        va[nt] = m16 * 64 + ((kc ^ (m16 & 7)) * 8) + (quad & 1) * 4;
    }

    // stage tile pair {2*pair, 2*pair+1}: 32 segs of 1KB, 4 per wave.
    // waves 0,1: K_even  2,3: V_even  4,5: K_odd  6,7: V_odd
    auto issueDMA = [&](int pair, int buf) {
        const int mat = wave >> 1;              // 0..3
        const int tt = pair * 2 + (mat >> 1);   // 64-key tile index
        unsigned short* dstb = &L[buf][mat * 4096];
        if ((mat & 1) == 0) {
            const unsigned short* kt = kbase + (size_t)tt * 64 * (3 * D_);
            #pragma unroll
            for (int i = 0; i < 4; ++i) {
                int gi = (wave & 1) * 4 + i;    // seg 0..7
                gl2lds16(kt + (size_t)(gi * 8 + lr8) * (3 * D_) + lsrc * 8,
                         dstb + gi * 512);
            }
        } else {
            const unsigned short* vtt = vtbase + tt * 64;
            #pragma unroll
            for (int i = 0; i < 4; ++i) {
                int gi = (wave & 1) * 4 + i;    // d-row group 0..7
                gl2lds16(vtt + (size_t)(gi * 8 + lr8) * S_ + lsrc * 8,
                         dstb + gi * 512);
            }
        }
    };

    issueDMA(0, 0);
    __asm__ volatile("s_waitcnt vmcnt(0)" ::: "memory");
    __syncthreads();
    issueDMA(1, 1);

    for (int s = 0; s < 16; ++s) {
        const int buf = s & 1;
        const unsigned short* Kp = &L[buf][grp * 8192];
        const unsigned short* Vp = Kp + 4096;

        // S^T = K·Q^T over this wave's 64-key tile, p = exp2(z)
        bf16x4 pf[2][4];
        #pragma unroll
        for (int nt = 0; nt < 4; ++nt) {
            bf16x8 kf0 = *(const bf16x8*)&Kp[kaddr0 + nt * 1024];
            bf16x8 kf1 = *(const bf16x8*)&Kp[kaddr1 + nt * 1024];
            #pragma unroll
            for (int g = 0; g < 2; ++g) {
                f32x4 z = {0.f, 0.f, 0.f, 0.f};
                z = MFMA32(kf0, qf0[g], z);
                z = MFMA32(kf1, qf1[g], z);
                float p0 = __builtin_amdgcn_exp2f(z[0]);
                float p1 = __builtin_amdgcn_exp2f(z[1]);
                float p2 = __builtin_amdgcn_exp2f(z[2]);
                float p3 = __builtin_amdgcn_exp2f(z[3]);
                union { unsigned u[2]; bf16x4 v; } pk;
                pk.u[0] = pk2bf(p0, p1);
                pk.u[1] = pk2bf(p2, p3);
                pf[g][nt] = pk.v;
                ol[g] = MFMA16(pf[g][nt], onesf, ol[g]);  // row-sum of rounded p
            }
        }

        // O += P·V via 16x16x16
        #pragma unroll
        for (int nt = 0; nt < 4; ++nt)
            #pragma unroll
            for (int dt = 0; dt < 4; ++dt) {
                bf16x4 vf = *(const bf16x4*)&Vp[va[nt] + dt * 1024];
                o[0][dt] = MFMA16(pf[0][nt], vf, o[0][dt]);
                o[1][dt] = MFMA16(pf[1][nt], vf, o[1][dt]);
            }

        // DMA(s+1) had all of compute(s) to land; drain; refill freed buf
        __asm__ volatile("s_waitcnt vmcnt(0)" ::: "memory");
        __syncthreads();
        if (s + 2 < 16) issueDMA(s + 2, buf);
    }

    // merge: group B dumps partials to LDS; group A adds, normalizes, writes.
    // stride 44 floats/lane (16B-aligned, breaks pow2 bank pattern).
    float* M = (float*)&L[0][0];
    const int mb = (qw * 64 + lane) * 44;
    if (grp == 1) {
        #pragma unroll
        for (int g = 0; g < 2; ++g) {
            #pragma unroll
            for (int dt = 0; dt < 4; ++dt)
                *(f32x4*)&M[mb + (g * 4 + dt) * 4] = o[g][dt];
            *(f32x4*)&M[mb + 32 + g * 4] = ol[g];
        }
    }
    __syncthreads();
    if (grp == 0) {
        #pragma unroll
        for (int g = 0; g < 2; ++g) {
            #pragma unroll
            for (int dt = 0; dt < 4; ++dt)
                o[g][dt] += *(const f32x4*)&M[mb + (g * 4 + dt) * 4];
            ol[g] += *(const f32x4*)&M[mb + 32 + g * 4];
        }
        #pragma unroll
        for (int g = 0; g < 2; ++g)
            #pragma unroll
            for (int r = 0; r < 4; ++r) {
                float inv = 1.f / ol[g][r];
                size_t row = (size_t)b * S_ + q0 + qw * 32 + g * 16 + quad * 4 + r;
                unsigned short* op = out + row * D_ + h * HD_;
                #pragma unroll
                for (int dt = 0; dt < 4; ++dt)
                    op[dt * 16 + m16] = f2bf(o[g][dt][r] * inv);
            }
    }
}

// ---------------------------------------------------------------------------
extern "C" void kernel_launch(void* const* d_in, const int* in_sizes, int n_in,
                              void* d_out, int out_size, void* d_ws, size_t ws_size,
                              hipStream_t stream) {
    const float* x     = (const float*)d_in[0];
    const float* w_qkv = (const float*)d_in[1];
    const float* w_out = (const float*)d_in[2];
    float* out = (float*)d_out;

    const size_t n_x = (size_t)B_ * S_ * D_;
    const size_t n_wqkv = (size_t)3 * D_ * D_;
    const size_t n_wout = (size_t)D_ * D_;

    unsigned short* xb    = (unsigned short*)d_ws;
    unsigned short* wqkvb = xb + n_x;
    unsigned short* woutb = wqkvb + n_wqkv;
    unsigned short* qkvb  = woutb + n_wout;                    // [B,S,3D]
    unsigned short* attnb = qkvb + (size_t)B_ * S_ * 3 * D_;   // [B,S,D]
    unsigned short* vtb   = attnb + n_x;                       // [B*H*64, S]

    dim3 blk(256);

    cvt_all<<<2048, blk, 0, stream>>>(x, w_qkv, w_out, xb, wqkvb, woutb);

    // qkv = x @ w_qkv^T : M=4096, N=3072, K=1024 (bf16 out).
    // V-section blocks write transposed directly into vtb (fused transpose).
    gemm_nt_b<128><<<dim3(3 * D_ / 128, B_ * S_ / 128), blk, 0, stream>>>(
        xb, wqkvb, qkvb, vtb, B_ * S_, 3 * D_, D_, 1);

    // attention: 512 XCD-swizzled blocks, 8 waves (key-split 2x4x32q)
    attn_mfma<<<512, dim3(512), 0, stream>>>(qkvb, vtb, attnb);

    // out = attn_out @ w_out^T : M=4096, N=1024, K=1024 (fp32 out, BN=64)
    gemm_nt_b<64><<<dim3(D_ / 64, B_ * S_ / 128), blk, 0, stream>>>(
        attnb, woutb, out, nullptr, B_ * S_, D_, D_, 0);
}

// Round 7
// 180.642 us; speedup vs baseline: 1.1093x; 1.1093x over previous
//
#include <hip/hip_runtime.h>
#include <hip/hip_bf16.h>
#include <math.h>

#define B_ 2
#define S_ 2048
#define D_ 1024
#define H_ 16
#define HD_ 64

typedef short bf16x8 __attribute__((ext_vector_type(8)));
typedef short bf16x4 __attribute__((ext_vector_type(4)));
typedef float f32x4 __attribute__((ext_vector_type(4)));

#define MFMA32(a, b, c) __builtin_amdgcn_mfma_f32_16x16x32_bf16(a, b, c, 0, 0, 0)
#define MFMA16(a, b, c) __builtin_amdgcn_mfma_f32_16x16x16bf16_1k(a, b, c, 0, 0, 0)

static __device__ __forceinline__ unsigned short f2bf(float f) {
    union { float f; unsigned u; } v = {f};
    return (unsigned short)((v.u + 0x7fffu + ((v.u >> 16) & 1u)) >> 16);
}

static __device__ __forceinline__ unsigned pk2bf(float a, float b) {
    __hip_bfloat162 h = __float22bfloat162_rn(make_float2(a, b));
    unsigned r;
    __builtin_memcpy(&r, &h, 4);
    return r;
}

static __device__ __forceinline__ void gl2lds16(const void* g, void* l) {
    __builtin_amdgcn_global_load_lds((const __attribute__((address_space(1))) unsigned int*)g,
                                     (__attribute__((address_space(3))) unsigned int*)l,
                                     16, 0, 0);
}

// scale all 8 bf16 lanes of a fragment by s (fp32 math, RNE repack)
static __device__ __forceinline__ bf16x8 scaleQ(bf16x8 v, float s) {
    union { bf16x8 v; unsigned u[4]; } a, r;
    a.v = v;
    #pragma unroll
    for (int i = 0; i < 4; ++i) {
        float lo = __uint_as_float(a.u[i] << 16);
        float hi = __uint_as_float(a.u[i] & 0xffff0000u);
        r.u[i] = pk2bf(lo * s, hi * s);
    }
    return r.v;
}

// ---------------------------------------------------------------------------
// fused fp32 -> bf16 convert for all three inputs (RNE)
// ---------------------------------------------------------------------------
__global__ __launch_bounds__(256) void cvt_all(const float* __restrict__ x,
                                               const float* __restrict__ wq,
                                               const float* __restrict__ wo,
                                               unsigned short* __restrict__ xb,
                                               unsigned short* __restrict__ wqb,
                                               unsigned short* __restrict__ wob) {
    const int N0 = 1048576, N1 = 786432, N2 = 262144;  // float4 counts
    int stride = gridDim.x * blockDim.x;
    for (int i = blockIdx.x * blockDim.x + threadIdx.x; i < N0 + N1 + N2; i += stride) {
        const float4* src; ushort4* dst; int j;
        if (i < N0)            { src = (const float4*)x;  dst = (ushort4*)xb;  j = i; }
        else if (i < N0 + N1)  { src = (const float4*)wq; dst = (ushort4*)wqb; j = i - N0; }
        else                   { src = (const float4*)wo; dst = (ushort4*)wob; j = i - N0 - N1; }
        float4 v = src[j];
        ushort4 o;
        o.x = f2bf(v.x); o.y = f2bf(v.y); o.z = f2bf(v.z); o.w = f2bf(v.w);
        dst[j] = o;
    }
}

// ---------------------------------------------------------------------------
// bf16 NT GEMM. BK=64 (barrier-amortized m97 structure): 2x MFMA per
// barrier pair, half the K-steps vs BK=32. 128B rows would be a 16-way
// bank conflict on ds_read_b128 (G4), so the attn kernel's PROVEN XOR
// chunk-swizzle is used: pre-swizzled DMA source (lsrc = (lane&7)^lr8,
// linear LDS dest) + swizzled read addr ((quad^(row&7))*8, ^32 for the
// second k-half). Single-buffered LDS (dbuf is a measured null on this
// structure, R6/m99). No XCD swizzle (L3-fit => ~2% harm, R6/m160).
// Fused V-transpose epilogue (QKV projection): V-section blocks
// (col0 >= 2*D_) write transposed into vt, skip qkvb.
// ---------------------------------------------------------------------------
template <int BN>
__global__ __launch_bounds__(256) void gemm_nt_b(const unsigned short* __restrict__ A,
                                                 const unsigned short* __restrict__ Bm,
                                                 void* __restrict__ Cout,
                                                 unsigned short* __restrict__ vtout,
                                                 int M, int N, int K, int c_bf16) {
    constexpr int BM = 128, BK = 64;
    constexpr int MI = (BN == 128) ? 4 : 2;
    constexpr int NI = 4;
    constexpr int ASEG = BM / 8;            // 16 segs of 8 rows (1 KB each)
    constexpr int SEGS = (BM + BN) / 8;     // 32 (BN=128) or 24 (BN=64)
    __shared__ unsigned short As[BM * BK];  // 16 KB, chunk-swizzled rows
    __shared__ unsigned short Bs[BN * BK];  // 16/8 KB

    const int tid = threadIdx.x;
    const int wave = tid >> 6, lane = tid & 63;
    const int m16 = lane & 15, quad = lane >> 4;
    const int wrow = (BN == 128) ? (wave >> 1) * 64 : wave * 32;
    const int wcol = (BN == 128) ? (wave & 1) * 64 : 0;
    const int row0 = blockIdx.y * BM, col0 = blockIdx.x * BN;

    const int lr8 = lane >> 3;           // row within 8-row seg
    const int lsrc = (lane & 7) ^ lr8;   // source chunk for swizzled DMA

    const int ka = (quad ^ (m16 & 7)) * 8;  // swizzled chunk offset (shorts)

    f32x4 acc[MI][NI] = {};

    const int nk = K / BK;               // 16 steps for K=1024
    for (int kk = 0; kk < nk; ++kk) {
        __syncthreads();
        for (int s = wave; s < SEGS; s += 4) {
            if (s < ASEG) {
                gl2lds16(&A[(size_t)(row0 + s * 8 + lr8) * K + kk * BK + lsrc * 8],
                         &As[s * 8 * BK]);
            } else {
                int t = s - ASEG;
                gl2lds16(&Bm[(size_t)(col0 + t * 8 + lr8) * K + kk * BK + lsrc * 8],
                         &Bs[t * 8 * BK]);
            }
        }
        __asm__ volatile("s_waitcnt vmcnt(0)" ::: "memory");
        __syncthreads();

        bf16x8 af0[MI], af1[MI], bf0[NI], bf1[NI];
        #pragma unroll
        for (int mi = 0; mi < MI; ++mi) {
            int a = (wrow + mi * 16 + m16) * BK + ka;
            af0[mi] = *(const bf16x8*)&As[a];
            af1[mi] = *(const bf16x8*)&As[a ^ 32];
        }
        #pragma unroll
        for (int ni = 0; ni < NI; ++ni) {
            int a = (wcol + ni * 16 + m16) * BK + ka;
            bf0[ni] = *(const bf16x8*)&Bs[a];
            bf1[ni] = *(const bf16x8*)&Bs[a ^ 32];
        }
        #pragma unroll
        for (int mi = 0; mi < MI; ++mi)
            #pragma unroll
            for (int ni = 0; ni < NI; ++ni) {
                acc[mi][ni] = MFMA32(af0[mi], bf0[ni], acc[mi][ni]);
                acc[mi][ni] = MFMA32(af1[mi], bf1[ni], acc[mi][ni]);
            }
    }

    if (vtout != nullptr && col0 >= 2 * D_) {
        // V block of the QKV projection: write transposed into vt only.
        #pragma unroll
        for (int mi = 0; mi < MI; ++mi) {
            int srow = row0 + wrow + mi * 16 + quad * 4;   // b*2048 + s
            int bb = srow >> 11;
            int s = srow & (S_ - 1);
            #pragma unroll
            for (int ni = 0; ni < NI; ++ni) {
                int hd = col0 + wcol + ni * 16 + m16 - 2 * D_;  // 0..1023
                ushort4 v4;
                v4.x = f2bf(acc[mi][ni][0]);
                v4.y = f2bf(acc[mi][ni][1]);
                v4.z = f2bf(acc[mi][ni][2]);
                v4.w = f2bf(acc[mi][ni][3]);
                *(ushort4*)&vtout[((size_t)(bb * 16 + (hd >> 6)) * 64 + (hd & 63)) * S_ + s] = v4;
            }
        }
        return;
    }

    #pragma unroll
    for (int mi = 0; mi < MI; ++mi) {
        #pragma unroll
        for (int r = 0; r < 4; ++r) {
            size_t grow = row0 + wrow + mi * 16 + quad * 4 + r;
            #pragma unroll
            for (int ni = 0; ni < NI; ++ni) {
                size_t gcol = col0 + wcol + ni * 16 + m16;
                if (c_bf16)
                    ((unsigned short*)Cout)[grow * N + gcol] = f2bf(acc[mi][ni][r]);
                else
                    ((float*)Cout)[grow * N + gcol] = acc[mi][ni][r];
            }
        }
    }
}

// ---------------------------------------------------------------------------
// MFMA flash attention, key-split wave groups (R3/R5 verified: ~57 us).
// 512 threads = 8 waves. Waves 0-3 own q-subtiles of 32 queries and
// process EVEN 64-key tiles; waves 4-7 the SAME queries, ODD tiles.
// KT=64 pairs: live set 64KB -> 2 blocks/CU, 4 waves/SIMD. exp2-softmax
// has no running max, so partials merge by addition in LDS.
// Pipeline: compute(t) with DMA(t+1) in flight; vmcnt(0); barrier; DMA(t+2).
// NEW: s_setprio(1) around the PV MFMA cluster (T5, attn-positive m191);
// hoisted zero accumulator for the z-inits.
// ---------------------------------------------------------------------------
__global__ __launch_bounds__(512, 4) void attn_mfma(const unsigned short* __restrict__ qkv,
                                                    const unsigned short* __restrict__ vt,
                                                    unsigned short* __restrict__ out) {
    // [buf][ K_even(4096) | V_even(4096) | K_odd(4096) | V_odd(4096) ] shorts
    __shared__ unsigned short L[2][16384];

    const int id = blockIdx.x;
    const int bh = ((id >> 3) & 3) * 8 + (id & 7);
    const int b = bh >> 4, h = bh & 15;
    const int q0 = (id >> 5) * 128;

    const int tid = threadIdx.x;
    const int wave = tid >> 6, lane = tid & 63;  // wave 0..7
    const int grp = wave >> 2;                   // 0: even tiles, 1: odd tiles
    const int qw = wave & 3;                     // q-subtile (32 q each)
    const int m16 = lane & 15, quad = lane >> 4;

    const float QS = 0.125f * 1.44269504089f;  // scale * log2(e), folded into Q

    bf16x8 qf0[2], qf1[2];
    #pragma unroll
    for (int g = 0; g < 2; ++g) {
        const unsigned short* qrow =
            qkv + ((size_t)b * S_ + q0 + qw * 32 + g * 16 + m16) * (3 * D_) + h * HD_;
        qf0[g] = scaleQ(*(const bf16x8*)(qrow + quad * 8), QS);
        qf1[g] = scaleQ(*(const bf16x8*)(qrow + 32 + quad * 8), QS);
    }

    f32x4 o[2][4] = {};
    f32x4 ol[2] = {};
    const f32x4 zf = {};
    const bf16x4 onesf = {(short)0x3F80, (short)0x3F80, (short)0x3F80, (short)0x3F80};

    const unsigned short* kbase = qkv + (size_t)b * S_ * 3 * D_ + D_ + h * HD_;
    const unsigned short* vtbase = vt + (size_t)bh * 64 * S_;

    const int lr8 = lane >> 3;           // row-in-8-group
    const int lsrc = (lane & 7) ^ lr8;   // source chunk for swizzled DMA

    // loop-invariant LDS read offsets (shorts, within a 4096-short region)
    const int kaddr0 = m16 * 64 + ((quad ^ (m16 & 7)) * 8);
    const int kaddr1 = kaddr0 ^ 32;
    int va[4];
    #pragma unroll
    for (int nt = 0; nt < 4; ++nt) {
        int kc = nt * 2 + (quad >> 1);
        va[nt] = m16 * 64 + ((kc ^ (m16 & 7)) * 8) + (quad & 1) * 4;
    }

    // stage tile pair {2*pair, 2*pair+1}: 32 segs of 1KB, 4 per wave.
    // waves 0,1: K_even  2,3: V_even  4,5: K_odd  6,7: V_odd
    auto issueDMA = [&](int pair, int buf) {
        const int mat = wave >> 1;              // 0..3
        const int tt = pair * 2 + (mat >> 1);   // 64-key tile index
        unsigned short* dstb = &L[buf][mat * 4096];
        if ((mat & 1) == 0) {
            const unsigned short* kt = kbase + (size_t)tt * 64 * (3 * D_);
            #pragma unroll
            for (int i = 0; i < 4; ++i) {
                int gi = (wave & 1) * 4 + i;    // seg 0..7
                gl2lds16(kt + (size_t)(gi * 8 + lr8) * (3 * D_) + lsrc * 8,
                         dstb + gi * 512);
            }
        } else {
            const unsigned short* vtt = vtbase + tt * 64;
            #pragma unroll
            for (int i = 0; i < 4; ++i) {
                int gi = (wave & 1) * 4 + i;    // d-row group 0..7
                gl2lds16(vtt + (size_t)(gi * 8 + lr8) * S_ + lsrc * 8,
                         dstb + gi * 512);
            }
        }
    };

    issueDMA(0, 0);
    __asm__ volatile("s_waitcnt vmcnt(0)" ::: "memory");
    __syncthreads();
    issueDMA(1, 1);

    for (int s = 0; s < 16; ++s) {
        const int buf = s & 1;
        const unsigned short* Kp = &L[buf][grp * 8192];
        const unsigned short* Vp = Kp + 4096;

        // S^T = K·Q^T over this wave's 64-key tile, p = exp2(z)
        bf16x4 pf[2][4];
        #pragma unroll
        for (int nt = 0; nt < 4; ++nt) {
            bf16x8 kf0 = *(const bf16x8*)&Kp[kaddr0 + nt * 1024];
            bf16x8 kf1 = *(const bf16x8*)&Kp[kaddr1 + nt * 1024];
            #pragma unroll
            for (int g = 0; g < 2; ++g) {
                f32x4 z = MFMA32(kf0, qf0[g], zf);
                z = MFMA32(kf1, qf1[g], z);
                float p0 = __builtin_amdgcn_exp2f(z[0]);
                float p1 = __builtin_amdgcn_exp2f(z[1]);
                float p2 = __builtin_amdgcn_exp2f(z[2]);
                float p3 = __builtin_amdgcn_exp2f(z[3]);
                union { unsigned u[2]; bf16x4 v; } pk;
                pk.u[0] = pk2bf(p0, p1);
                pk.u[1] = pk2bf(p2, p3);
                pf[g][nt] = pk.v;
                ol[g] = MFMA16(pf[g][nt], onesf, ol[g]);  // row-sum of rounded p
            }
        }

        // O += P·V via 16x16x16 (pure-MFMA cluster: prefer on CU scheduler)
        __builtin_amdgcn_s_setprio(1);
        #pragma unroll
        for (int nt = 0; nt < 4; ++nt)
            #pragma unroll
            for (int dt = 0; dt < 4; ++dt) {
                bf16x4 vf = *(const bf16x4*)&Vp[va[nt] + dt * 1024];
                o[0][dt] = MFMA16(pf[0][nt], vf, o[0][dt]);
                o[1][dt] = MFMA16(pf[1][nt], vf, o[1][dt]);
            }
        __builtin_amdgcn_s_setprio(0);

        // DMA(s+1) had all of compute(s) to land; drain; refill freed buf
        __asm__ volatile("s_waitcnt vmcnt(0)" ::: "memory");
        __syncthreads();
        if (s + 2 < 16) issueDMA(s + 2, buf);
    }

    // merge: group B dumps partials to LDS; group A adds, normalizes, writes.
    // stride 44 floats/lane (16B-aligned, breaks pow2 bank pattern).
    float* M = (float*)&L[0][0];
    const int mb = (qw * 64 + lane) * 44;
    if (grp == 1) {
        #pragma unroll
        for (int g = 0; g < 2; ++g) {
            #pragma unroll
            for (int dt = 0; dt < 4; ++dt)
                *(f32x4*)&M[mb + (g * 4 + dt) * 4] = o[g][dt];
            *(f32x4*)&M[mb + 32 + g * 4] = ol[g];
        }
    }
    __syncthreads();
    if (grp == 0) {
        #pragma unroll
        for (int g = 0; g < 2; ++g) {
            #pragma unroll
            for (int dt = 0; dt < 4; ++dt)
                o[g][dt] += *(const f32x4*)&M[mb + (g * 4 + dt) * 4];
            ol[g] += *(const f32x4*)&M[mb + 32 + g * 4];
        }
        #pragma unroll
        for (int g = 0; g < 2; ++g)
            #pragma unroll
            for (int r = 0; r < 4; ++r) {
                float inv = 1.f / ol[g][r];
                size_t row = (size_t)b * S_ + q0 + qw * 32 + g * 16 + quad * 4 + r;
                unsigned short* op = out + row * D_ + h * HD_;
                #pragma unroll
                for (int dt = 0; dt < 4; ++dt)
                    op[dt * 16 + m16] = f2bf(o[g][dt][r] * inv);
            }
    }
}

// ---------------------------------------------------------------------------
extern "C" void kernel_launch(void* const* d_in, const int* in_sizes, int n_in,
                              void* d_out, int out_size, void* d_ws, size_t ws_size,
                              hipStream_t stream) {
    const float* x     = (const float*)d_in[0];
    const float* w_qkv = (const float*)d_in[1];
    const float* w_out = (const float*)d_in[2];
    float* out = (float*)d_out;

    const size_t n_x = (size_t)B_ * S_ * D_;
    const size_t n_wqkv = (size_t)3 * D_ * D_;
    const size_t n_wout = (size_t)D_ * D_;

    unsigned short* xb    = (unsigned short*)d_ws;
    unsigned short* wqkvb = xb + n_x;
    unsigned short* woutb = wqkvb + n_wqkv;
    unsigned short* qkvb  = woutb + n_wout;                    // [B,S,3D]
    unsigned short* attnb = qkvb + (size_t)B_ * S_ * 3 * D_;   // [B,S,D]
    unsigned short* vtb   = attnb + n_x;                       // [B*H*64, S]

    dim3 blk(256);

    cvt_all<<<2048, blk, 0, stream>>>(x, w_qkv, w_out, xb, wqkvb, woutb);

    // qkv = x @ w_qkv^T : M=4096, N=3072, K=1024 (bf16 out).
    // V-section blocks write transposed directly into vtb (fused transpose).
    gemm_nt_b<128><<<dim3(3 * D_ / 128, B_ * S_ / 128), blk, 0, stream>>>(
        xb, wqkvb, qkvb, vtb, B_ * S_, 3 * D_, D_, 1);

    // attention: 512 XCD-swizzled blocks, 8 waves (key-split 2x4x32q)
    attn_mfma<<<512, dim3(512), 0, stream>>>(qkvb, vtb, attnb);

    // out = attn_out @ w_out^T : M=4096, N=1024, K=1024 (fp32 out, BN=64)
    gemm_nt_b<64><<<dim3(D_ / 64, B_ * S_ / 128), blk, 0, stream>>>(
        attnb, woutb, out, nullptr, B_ * S_, D_, D_, 0);
}

// Round 8
// 176.739 us; speedup vs baseline: 1.1338x; 1.0221x over previous
//
#include <hip/hip_runtime.h>
#include <hip/hip_bf16.h>
#include <math.h>

#define B_ 2
#define S_ 2048
#define D_ 1024
#define H_ 16
#define HD_ 64

typedef short bf16x8 __attribute__((ext_vector_type(8)));
typedef short bf16x4 __attribute__((ext_vector_type(4)));
typedef float f32x4 __attribute__((ext_vector_type(4)));

#define MFMA32(a, b, c) __builtin_amdgcn_mfma_f32_16x16x32_bf16(a, b, c, 0, 0, 0)
#define MFMA16(a, b, c) __builtin_amdgcn_mfma_f32_16x16x16bf16_1k(a, b, c, 0, 0, 0)

static __device__ __forceinline__ unsigned short f2bf(float f) {
    union { float f; unsigned u; } v = {f};
    return (unsigned short)((v.u + 0x7fffu + ((v.u >> 16) & 1u)) >> 16);
}

static __device__ __forceinline__ unsigned pk2bf(float a, float b) {
    __hip_bfloat162 h = __float22bfloat162_rn(make_float2(a, b));
    unsigned r;
    __builtin_memcpy(&r, &h, 4);
    return r;
}

static __device__ __forceinline__ void gl2lds16(const void* g, void* l) {
    __builtin_amdgcn_global_load_lds((const __attribute__((address_space(1))) unsigned int*)g,
                                     (__attribute__((address_space(3))) unsigned int*)l,
                                     16, 0, 0);
}

// scale all 8 bf16 lanes of a fragment by s (fp32 math, RNE repack)
static __device__ __forceinline__ bf16x8 scaleQ(bf16x8 v, float s) {
    union { bf16x8 v; unsigned u[4]; } a, r;
    a.v = v;
    #pragma unroll
    for (int i = 0; i < 4; ++i) {
        float lo = __uint_as_float(a.u[i] << 16);
        float hi = __uint_as_float(a.u[i] & 0xffff0000u);
        r.u[i] = pk2bf(lo * s, hi * s);
    }
    return r.v;
}

// ---------------------------------------------------------------------------
// fused fp32 -> bf16 convert for all three inputs (RNE)
// ---------------------------------------------------------------------------
__global__ __launch_bounds__(256) void cvt_all(const float* __restrict__ x,
                                               const float* __restrict__ wq,
                                               const float* __restrict__ wo,
                                               unsigned short* __restrict__ xb,
                                               unsigned short* __restrict__ wqb,
                                               unsigned short* __restrict__ wob) {
    const int N0 = 1048576, N1 = 786432, N2 = 262144;  // float4 counts
    int stride = gridDim.x * blockDim.x;
    for (int i = blockIdx.x * blockDim.x + threadIdx.x; i < N0 + N1 + N2; i += stride) {
        const float4* src; ushort4* dst; int j;
        if (i < N0)            { src = (const float4*)x;  dst = (ushort4*)xb;  j = i; }
        else if (i < N0 + N1)  { src = (const float4*)wq; dst = (ushort4*)wqb; j = i - N0; }
        else                   { src = (const float4*)wo; dst = (ushort4*)wob; j = i - N0 - N1; }
        float4 v = src[j];
        ushort4 o;
        o.x = f2bf(v.x); o.y = f2bf(v.y); o.z = f2bf(v.z); o.w = f2bf(v.w);
        dst[j] = o;
    }
}

// ---------------------------------------------------------------------------
// bf16 NT GEMM, BK=64 barrier-amortized (R7 win), XOR chunk-swizzled LDS
// (pre-swizzled DMA source + swizzled read; both-sides rule). 2x2 wave
// grid of (BM/2)x(BN/2) each. NEW (R8): K-half fragment split -- load 6
// frags, 16 MFMA, load 6 frags, 16 MFMA -- halves fragment liveness so
// __launch_bounds__(256,4) holds VGPR<=128 -> 4 waves/SIMD (was 2-3):
// more co-resident blocks to hide the per-step vmcnt(0) drain.
// Single-buffered LDS (dbuf null: R6/m99). No XCD swizzle (L3-fit: m160).
// Fused V-transpose epilogue for the QKV projection (col0 >= 2*D_).
// ---------------------------------------------------------------------------
template <int BM, int BN>
__global__ __launch_bounds__(256, 4) void gemm_nt_b(const unsigned short* __restrict__ A,
                                                    const unsigned short* __restrict__ Bm,
                                                    void* __restrict__ Cout,
                                                    unsigned short* __restrict__ vtout,
                                                    int M, int N, int K, int c_bf16) {
    constexpr int BK = 64;
    constexpr int MI = BM / 32;
    constexpr int NI = BN / 32;
    constexpr int ASEG = BM / 8;            // 1 KB segs of 8 rows
    constexpr int SEGS = (BM + BN) / 8;
    __shared__ unsigned short As[BM * BK];
    __shared__ unsigned short Bs[BN * BK];

    const int tid = threadIdx.x;
    const int wave = tid >> 6, lane = tid & 63;
    const int m16 = lane & 15, quad = lane >> 4;
    const int wrow = (wave >> 1) * (BM / 2);
    const int wcol = (wave & 1) * (BN / 2);
    const int row0 = blockIdx.y * BM, col0 = blockIdx.x * BN;

    const int lr8 = lane >> 3;           // row within 8-row seg
    const int lsrc = (lane & 7) ^ lr8;   // source chunk for swizzled DMA

    const int ka = (quad ^ (m16 & 7)) * 8;  // swizzled chunk offset (shorts)

    f32x4 acc[MI][NI] = {};

    const int nk = K / BK;
    for (int kk = 0; kk < nk; ++kk) {
        __syncthreads();
        for (int s = wave; s < SEGS; s += 4) {
            if (s < ASEG) {
                gl2lds16(&A[(size_t)(row0 + s * 8 + lr8) * K + kk * BK + lsrc * 8],
                         &As[s * 8 * BK]);
            } else {
                int t = s - ASEG;
                gl2lds16(&Bm[(size_t)(col0 + t * 8 + lr8) * K + kk * BK + lsrc * 8],
                         &Bs[t * 8 * BK]);
            }
        }
        __asm__ volatile("s_waitcnt vmcnt(0)" ::: "memory");
        __syncthreads();

        // K-half split: only MI+NI fragments live at a time
        #pragma unroll
        for (int kh = 0; kh < 2; ++kh) {
            bf16x8 af[MI], bfr[NI];
            #pragma unroll
            for (int mi = 0; mi < MI; ++mi)
                af[mi] = *(const bf16x8*)&As[((wrow + mi * 16 + m16) * BK + ka) ^ (kh * 32)];
            #pragma unroll
            for (int ni = 0; ni < NI; ++ni)
                bfr[ni] = *(const bf16x8*)&Bs[((wcol + ni * 16 + m16) * BK + ka) ^ (kh * 32)];
            #pragma unroll
            for (int mi = 0; mi < MI; ++mi)
                #pragma unroll
                for (int ni = 0; ni < NI; ++ni)
                    acc[mi][ni] = MFMA32(af[mi], bfr[ni], acc[mi][ni]);
        }
    }

    if (vtout != nullptr && col0 >= 2 * D_) {
        // V block of the QKV projection: write transposed into vt only.
        #pragma unroll
        for (int mi = 0; mi < MI; ++mi) {
            int srow = row0 + wrow + mi * 16 + quad * 4;   // b*2048 + s
            int bb = srow >> 11;
            int s = srow & (S_ - 1);
            #pragma unroll
            for (int ni = 0; ni < NI; ++ni) {
                int hd = col0 + wcol + ni * 16 + m16 - 2 * D_;  // 0..1023
                ushort4 v4;
                v4.x = f2bf(acc[mi][ni][0]);
                v4.y = f2bf(acc[mi][ni][1]);
                v4.z = f2bf(acc[mi][ni][2]);
                v4.w = f2bf(acc[mi][ni][3]);
                *(ushort4*)&vtout[((size_t)(bb * 16 + (hd >> 6)) * 64 + (hd & 63)) * S_ + s] = v4;
            }
        }
        return;
    }

    #pragma unroll
    for (int mi = 0; mi < MI; ++mi) {
        #pragma unroll
        for (int r = 0; r < 4; ++r) {
            size_t grow = row0 + wrow + mi * 16 + quad * 4 + r;
            #pragma unroll
            for (int ni = 0; ni < NI; ++ni) {
                size_t gcol = col0 + wcol + ni * 16 + m16;
                if (c_bf16)
                    ((unsigned short*)Cout)[grow * N + gcol] = f2bf(acc[mi][ni][r]);
                else
                    ((float*)Cout)[grow * N + gcol] = acc[mi][ni][r];
            }
        }
    }
}

// ---------------------------------------------------------------------------
// MFMA flash attention, key-split wave groups (R3/R5/R7 verified ~56 us).
// 512 threads = 8 waves. Waves 0-3 own q-subtiles of 32 queries and
// process EVEN 64-key tiles; waves 4-7 the SAME queries, ODD tiles.
// KT=64 pairs: live set 64KB -> 2 blocks/CU, 4 waves/SIMD. exp2-softmax
// has no running max, so partials merge by addition in LDS.
// Pipeline: compute(t) with DMA(t+1) in flight; vmcnt(0); barrier; DMA(t+2).
// s_setprio(1) around the PV MFMA cluster (T5, attn-positive).
// ---------------------------------------------------------------------------
__global__ __launch_bounds__(512, 4) void attn_mfma(const unsigned short* __restrict__ qkv,
                                                    const unsigned short* __restrict__ vt,
                                                    unsigned short* __restrict__ out) {
    // [buf][ K_even(4096) | V_even(4096) | K_odd(4096) | V_odd(4096) ] shorts
    __shared__ unsigned short L[2][16384];

    const int id = blockIdx.x;
    const int bh = ((id >> 3) & 3) * 8 + (id & 7);
    const int b = bh >> 4, h = bh & 15;
    const int q0 = (id >> 5) * 128;

    const int tid = threadIdx.x;
    const int wave = tid >> 6, lane = tid & 63;  // wave 0..7
    const int grp = wave >> 2;                   // 0: even tiles, 1: odd tiles
    const int qw = wave & 3;                     // q-subtile (32 q each)
    const int m16 = lane & 15, quad = lane >> 4;

    const float QS = 0.125f * 1.44269504089f;  // scale * log2(e), folded into Q

    bf16x8 qf0[2], qf1[2];
    #pragma unroll
    for (int g = 0; g < 2; ++g) {
        const unsigned short* qrow =
            qkv + ((size_t)b * S_ + q0 + qw * 32 + g * 16 + m16) * (3 * D_) + h * HD_;
        qf0[g] = scaleQ(*(const bf16x8*)(qrow + quad * 8), QS);
        qf1[g] = scaleQ(*(const bf16x8*)(qrow + 32 + quad * 8), QS);
    }

    f32x4 o[2][4] = {};
    f32x4 ol[2] = {};
    const f32x4 zf = {};
    const bf16x4 onesf = {(short)0x3F80, (short)0x3F80, (short)0x3F80, (short)0x3F80};

    const unsigned short* kbase = qkv + (size_t)b * S_ * 3 * D_ + D_ + h * HD_;
    const unsigned short* vtbase = vt + (size_t)bh * 64 * S_;

    const int lr8 = lane >> 3;           // row-in-8-group
    const int lsrc = (lane & 7) ^ lr8;   // source chunk for swizzled DMA

    // loop-invariant LDS read offsets (shorts, within a 4096-short region)
    const int kaddr0 = m16 * 64 + ((quad ^ (m16 & 7)) * 8);
    const int kaddr1 = kaddr0 ^ 32;
    int va[4];
    #pragma unroll
    for (int nt = 0; nt < 4; ++nt) {
        int kc = nt * 2 + (quad >> 1);
        va[nt] = m16 * 64 + ((kc ^ (m16 & 7)) * 8) + (quad & 1) * 4;
    }

    // stage tile pair {2*pair, 2*pair+1}: 32 segs of 1KB, 4 per wave.
    // waves 0,1: K_even  2,3: V_even  4,5: K_odd  6,7: V_odd
    auto issueDMA = [&](int pair, int buf) {
        const int mat = wave >> 1;              // 0..3
        const int tt = pair * 2 + (mat >> 1);   // 64-key tile index
        unsigned short* dstb = &L[buf][mat * 4096];
        if ((mat & 1) == 0) {
            const unsigned short* kt = kbase + (size_t)tt * 64 * (3 * D_);
            #pragma unroll
            for (int i = 0; i < 4; ++i) {
                int gi = (wave & 1) * 4 + i;    // seg 0..7
                gl2lds16(kt + (size_t)(gi * 8 + lr8) * (3 * D_) + lsrc * 8,
                         dstb + gi * 512);
            }
        } else {
            const unsigned short* vtt = vtbase + tt * 64;
            #pragma unroll
            for (int i = 0; i < 4; ++i) {
                int gi = (wave & 1) * 4 + i;    // d-row group 0..7
                gl2lds16(vtt + (size_t)(gi * 8 + lr8) * S_ + lsrc * 8,
                         dstb + gi * 512);
            }
        }
    };

    issueDMA(0, 0);
    __asm__ volatile("s_waitcnt vmcnt(0)" ::: "memory");
    __syncthreads();
    issueDMA(1, 1);

    for (int s = 0; s < 16; ++s) {
        const int buf = s & 1;
        const unsigned short* Kp = &L[buf][grp * 8192];
        const unsigned short* Vp = Kp + 4096;

        // S^T = K·Q^T over this wave's 64-key tile, p = exp2(z)
        bf16x4 pf[2][4];
        #pragma unroll
        for (int nt = 0; nt < 4; ++nt) {
            bf16x8 kf0 = *(const bf16x8*)&Kp[kaddr0 + nt * 1024];
            bf16x8 kf1 = *(const bf16x8*)&Kp[kaddr1 + nt * 1024];
            #pragma unroll
            for (int g = 0; g < 2; ++g) {
                f32x4 z = MFMA32(kf0, qf0[g], zf);
                z = MFMA32(kf1, qf1[g], z);
                float p0 = __builtin_amdgcn_exp2f(z[0]);
                float p1 = __builtin_amdgcn_exp2f(z[1]);
                float p2 = __builtin_amdgcn_exp2f(z[2]);
                float p3 = __builtin_amdgcn_exp2f(z[3]);
                union { unsigned u[2]; bf16x4 v; } pk;
                pk.u[0] = pk2bf(p0, p1);
                pk.u[1] = pk2bf(p2, p3);
                pf[g][nt] = pk.v;
                ol[g] = MFMA16(pf[g][nt], onesf, ol[g]);  // row-sum of rounded p
            }
        }

        // O += P·V via 16x16x16 (pure-MFMA cluster: prefer on CU scheduler)
        __builtin_amdgcn_s_setprio(1);
        #pragma unroll
        for (int nt = 0; nt < 4; ++nt)
            #pragma unroll
            for (int dt = 0; dt < 4; ++dt) {
                bf16x4 vf = *(const bf16x4*)&Vp[va[nt] + dt * 1024];
                o[0][dt] = MFMA16(pf[0][nt], vf, o[0][dt]);
                o[1][dt] = MFMA16(pf[1][nt], vf, o[1][dt]);
            }
        __builtin_amdgcn_s_setprio(0);

        // DMA(s+1) had all of compute(s) to land; drain; refill freed buf
        __asm__ volatile("s_waitcnt vmcnt(0)" ::: "memory");
        __syncthreads();
        if (s + 2 < 16) issueDMA(s + 2, buf);
    }

    // merge: group B dumps partials to LDS; group A adds, normalizes, writes.
    // stride 44 floats/lane (16B-aligned, breaks pow2 bank pattern).
    float* M = (float*)&L[0][0];
    const int mb = (qw * 64 + lane) * 44;
    if (grp == 1) {
        #pragma unroll
        for (int g = 0; g < 2; ++g) {
            #pragma unroll
            for (int dt = 0; dt < 4; ++dt)
                *(f32x4*)&M[mb + (g * 4 + dt) * 4] = o[g][dt];
            *(f32x4*)&M[mb + 32 + g * 4] = ol[g];
        }
    }
    __syncthreads();
    if (grp == 0) {
        #pragma unroll
        for (int g = 0; g < 2; ++g) {
            #pragma unroll
            for (int dt = 0; dt < 4; ++dt)
                o[g][dt] += *(const f32x4*)&M[mb + (g * 4 + dt) * 4];
            ol[g] += *(const f32x4*)&M[mb + 32 + g * 4];
        }
        #pragma unroll
        for (int g = 0; g < 2; ++g)
            #pragma unroll
            for (int r = 0; r < 4; ++r) {
                float inv = 1.f / ol[g][r];
                size_t row = (size_t)b * S_ + q0 + qw * 32 + g * 16 + quad * 4 + r;
                unsigned short* op = out + row * D_ + h * HD_;
                #pragma unroll
                for (int dt = 0; dt < 4; ++dt)
                    op[dt * 16 + m16] = f2bf(o[g][dt][r] * inv);
            }
    }
}

// ---------------------------------------------------------------------------
extern "C" void kernel_launch(void* const* d_in, const int* in_sizes, int n_in,
                              void* d_out, int out_size, void* d_ws, size_t ws_size,
                              hipStream_t stream) {
    const float* x     = (const float*)d_in[0];
    const float* w_qkv = (const float*)d_in[1];
    const float* w_out = (const float*)d_in[2];
    float* out = (float*)d_out;

    const size_t n_x = (size_t)B_ * S_ * D_;
    const size_t n_wqkv = (size_t)3 * D_ * D_;
    const size_t n_wout = (size_t)D_ * D_;

    unsigned short* xb    = (unsigned short*)d_ws;
    unsigned short* wqkvb = xb + n_x;
    unsigned short* woutb = wqkvb + n_wqkv;
    unsigned short* qkvb  = woutb + n_wout;                    // [B,S,3D]
    unsigned short* attnb = qkvb + (size_t)B_ * S_ * 3 * D_;   // [B,S,D]
    unsigned short* vtb   = attnb + n_x;                       // [B*H*64, S]

    dim3 blk(256);

    cvt_all<<<2048, blk, 0, stream>>>(x, w_qkv, w_out, xb, wqkvb, woutb);

    // qkv = x @ w_qkv^T : M=4096, N=3072, K=1024 (bf16 out).
    // V-section blocks write transposed directly into vtb (fused transpose).
    gemm_nt_b<128, 128><<<dim3(3 * D_ / 128, B_ * S_ / 128), blk, 0, stream>>>(
        xb, wqkvb, qkvb, vtb, B_ * S_, 3 * D_, D_, 1);

    // attention: 512 XCD-swizzled blocks, 8 waves (key-split 2x4x32q)
    attn_mfma<<<512, dim3(512), 0, stream>>>(qkvb, vtb, attnb);

    // out = attn_out @ w_out^T : M=4096, N=1024, K=1024 (fp32 out).
    // BM=BN=64 -> 1024 blocks (was 512): 4 blocks/CU, 4 waves/SIMD.
    gemm_nt_b<64, 64><<<dim3(D_ / 64, B_ * S_ / 64), blk, 0, stream>>>(
        attnb, woutb, out, nullptr, B_ * S_, D_, D_, 0);
}